// Round 2
// baseline (281.258 us; speedup 1.0000x reference)
//
#include <hip/hip_runtime.h>
#include <hip/hip_bf16.h>
#include <stdint.h>

#define OUTN   8192
#define INN    8192
#define NGRP   64
#define BATCHN 64
#define BN     64
#define BK     64
#define KSPLIT 8
#define KCHUNK (INN / KSPLIT)      /* 1024 k per ksplit chunk */
#define NITER  (KCHUNK / BK)       /* 16 iters of 64 k */
#define NGRPC  (KCHUNK / 128)      /* 8 quant-groups per chunk */

typedef __attribute__((ext_vector_type(8))) short bf16x8;
typedef __attribute__((ext_vector_type(8))) unsigned short u16x8;
typedef __attribute__((ext_vector_type(4))) float f32x4;
typedef __attribute__((ext_vector_type(4))) unsigned int u32x4;

__device__ __forceinline__ unsigned short f2bf(float f) {
  __hip_bfloat16 h = __float2bfloat16(f);
  return __builtin_bit_cast(unsigned short, h);
}
__device__ __forceinline__ float bf2f(unsigned short h) {
  unsigned int u = ((unsigned int)h) << 16;
  return __builtin_bit_cast(float, u);
}

// async global->LDS, 16B per lane; LDS dest = wave-uniform base + lane*16
__device__ __forceinline__ void gll16(const void* g, void* l) {
  __builtin_amdgcn_global_load_lds(
      (const __attribute__((address_space(1))) unsigned int*)g,
      (__attribute__((address_space(3))) unsigned int*)l, 16, 0, 0);
}

// Per batch row b: (1) x_bf16[b][k] = bf16(x[b][k]) written once (linear layout),
// (2) xsum[g][b] = sum over group g of bf16-rounded x
__global__ void qlin_prep(const float* __restrict__ x, float* __restrict__ xsum,
                          unsigned short* __restrict__ xbf) {
  const int b = blockIdx.x;
  const int t = threadIdx.x;
  const float* xrow = x + (size_t)b * INN + t * 32;
  unsigned short* orow = xbf + (size_t)b * INN + t * 32;
  float s = 0.0f;
#pragma unroll
  for (int c = 0; c < 4; ++c) {
    float4 v0 = *(const float4*)(xrow + c * 8);
    float4 v1 = *(const float4*)(xrow + c * 8 + 4);
    u16x8 h;
    h[0] = f2bf(v0.x); h[1] = f2bf(v0.y); h[2] = f2bf(v0.z); h[3] = f2bf(v0.w);
    h[4] = f2bf(v1.x); h[5] = f2bf(v1.y); h[6] = f2bf(v1.z); h[7] = f2bf(v1.w);
#pragma unroll
    for (int j = 0; j < 8; ++j) s += bf2f(h[j]);
    *(u16x8*)(orow + c * 8) = h;
  }
  __shared__ float parts[256];
  parts[t] = s;
  __syncthreads();
  if (t < NGRP) {
    float g = parts[4 * t] + parts[4 * t + 1] + parts[4 * t + 2] + parts[4 * t + 3];
    xsum[t * BATCHN + b] = g;
  }
}

// Tile geometry per iter: 64 rows x 128 B for both packed (32 int32 = 64 k) and
// x_bf16 (64 bf16). Row = 8 chunks of 16 B. Swizzle invariant (both tensors):
//   LDS slot (row, p) holds data chunk c = p ^ (row & 7)   [applied on the gll
//   SOURCE address, LDS dest stays linear — m173 pattern]
// Consumer reads chunk c of row r at slot r*8 + (c ^ (r&7)) -> 8 lanes per
// 4-bank group per wave b128 read = conflict-free minimum.
__global__ __launch_bounds__(256, 4) void qlin_main(
    const int* __restrict__ packed, const unsigned short* __restrict__ xbf,
    const float* __restrict__ scales, const float* __restrict__ xsum,
    float* __restrict__ out) {
  const int bx    = blockIdx.x;
  const int ks    = bx & (KSPLIT - 1);
  const int ntile = bx >> 3;
  const int o0    = ntile * BN;
  const int g0    = ks * NGRPC;

  const int t    = threadIdx.x;
  const int lane = t & 63;
  const int w    = t >> 6;        // wave 0..3 owns out cols [w*16, w*16+16)
  const int l15  = lane & 15;
  const int quad = lane >> 4;

  __shared__ __align__(16) int4  pkb[2][512];   // 2 x 8 KB raw packed ints
  __shared__ __align__(16) int4  xb[2][512];    // 2 x 8 KB x bf16
  __shared__ __align__(16) float st[BN][9];     // scales (pad 9 -> conflict-free)
  __shared__ __align__(16) float xs[NGRPC][BATCHN];

  // stage scales (64x8) and group x-sums (8x64) once
#pragma unroll
  for (int i = 0; i < 2; ++i) {
    int v = t * 2 + i;
    int ol = v >> 3, gl = v & 7;
    st[ol][gl] = scales[(size_t)(o0 + ol) * NGRP + g0 + gl];
    int gl2 = v >> 6, b2 = v & 63;
    xs[gl2][b2] = xsum[(g0 + gl2) * BATCHN + b2];
  }

  // gll source bases. Thread t covers LDS slots t (row t>>3) and 256+t (row +32).
  const int row0 = t >> 3;
  const int p0   = t & 7;
  const int c0   = p0 ^ (row0 & 7);          // swizzled data chunk
  const char* pk0 = (const char*)packed + (size_t)(o0 + row0) * 16384 + ks * 2048 + c0 * 16;
  const char* pk1 = pk0 + (size_t)32 * 16384;
  const char* xg0 = (const char*)xbf + (size_t)row0 * 16384 + ks * 2048 + c0 * 16;
  const char* xg1 = xg0 + (size_t)32 * 16384;

  auto issue = [&](int i, int buf) {
    const size_t off = (size_t)i * 128;
    gll16(pk0 + off, &pkb[buf][t]);
    gll16(pk1 + off, &pkb[buf][256 + t]);
    gll16(xg0 + off, &xb[buf][t]);
    gll16(xg1 + off, &xb[buf][256 + t]);
  };

  f32x4 facc[4], gacc[4];
#pragma unroll
  for (int mt = 0; mt < 4; ++mt) {
    facc[mt] = (f32x4){0.f, 0.f, 0.f, 0.f};
    gacc[mt] = (f32x4){0.f, 0.f, 0.f, 0.f};
  }

  issue(0, 0);
  __syncthreads();   // vmcnt drained before barrier -> tile 0 ready

  const int browB = w * 16 + l15;   // weight row = output column
  const int sw    = l15 & 7;        // consumer-side XOR
  int cur = 0;

  for (int g = 0; g < NGRPC; ++g) {
#pragma unroll
    for (int h = 0; h < 2; ++h) {
      const int i = g * 2 + h;
      if (i + 1 < NITER) issue(i + 1, cur ^ 1);   // in flight across the barrier

#pragma unroll
      for (int kq = 0; kq < 2; ++kq) {
        const int ch = kq * 4 + quad;             // data chunk: k = ch*8..ch*8+7
        int4 v = pkb[cur][browB * 8 + (ch ^ sw)];
        // byte n -> bf16x2 (128+lo_nibble, 128+hi_nibble); 0x4300 = 128.0bf
        u32x4 bw;
        bw.x = 0x43004300u | ((unsigned)v.x & 0xFu) | (((unsigned)v.x & 0xF0u) << 12);
        bw.y = 0x43004300u | ((unsigned)v.y & 0xFu) | (((unsigned)v.y & 0xF0u) << 12);
        bw.z = 0x43004300u | ((unsigned)v.z & 0xFu) | (((unsigned)v.z & 0xF0u) << 12);
        bw.w = 0x43004300u | ((unsigned)v.w & 0xFu) | (((unsigned)v.w & 0xF0u) << 12);
        bf16x8 bfv = __builtin_bit_cast(bf16x8, bw);
#pragma unroll
        for (int mt = 0; mt < 4; ++mt) {
          bf16x8 af = *(const bf16x8*)&xb[cur][(mt * 16 + l15) * 8 + (ch ^ sw)];
          gacc[mt] = __builtin_amdgcn_mfma_f32_16x16x32_bf16(af, bfv, gacc[mt], 0, 0, 0);
        }
      }

      if (h == 1) {
        // fold group g: y += s[o,g] * (S_g - 136 * xsum_g[b])   (136 = 128 + 8)
        float s0 = st[browB][g];
#pragma unroll
        for (int mt = 0; mt < 4; ++mt) {
          f32x4 xv = *(const f32x4*)&xs[g][mt * 16 + quad * 4];
#pragma unroll
          for (int r = 0; r < 4; ++r) {
            facc[mt][r] += s0 * (gacc[mt][r] - 136.0f * xv[r]);
            gacc[mt][r] = 0.f;
          }
        }
      }

      __syncthreads();   // drains next tile's glls (issued ~1 compute phase ago)
      cur ^= 1;
    }
  }

  // direct split-K accumulation: 8 ksplit blocks add into out (zeroed in launch).
  // Saves 16 MB part write + 16 MB part read + one kernel launch vs part path.
  const int obase = o0 + browB;
#pragma unroll
  for (int mt = 0; mt < 4; ++mt)
#pragma unroll
    for (int r = 0; r < 4; ++r) {
      int m = mt * 16 + quad * 4 + r;
      atomicAdd(&out[(size_t)m * OUTN + obase], facc[mt][r]);
    }
}

extern "C" void kernel_launch(void* const* d_in, const int* in_sizes, int n_in,
                              void* d_out, int out_size, void* d_ws, size_t ws_size,
                              hipStream_t stream) {
  const float* x      = (const float*)d_in[0];
  const int*   packed = (const int*)d_in[1];
  const float* scales = (const float*)d_in[2];
  float* out  = (float*)d_out;

  // ws layout: [0,16K) xsum | [16K, 16K+1M) x_bf16
  float*          xsum = (float*)d_ws;
  unsigned short* xbf  = (unsigned short*)((char*)d_ws + 16384);

  hipMemsetAsync(d_out, 0, (size_t)out_size * sizeof(float), stream);
  qlin_prep<<<BATCHN, 256, 0, stream>>>(x, xsum, xbf);
  qlin_main<<<(OUTN / BN) * KSPLIT, 256, 0, stream>>>(packed, xbf, scales, xsum, out);
}

// Round 3
// 212.339 us; speedup vs baseline: 1.3246x; 1.3246x over previous
//
#include <hip/hip_runtime.h>
#include <hip/hip_bf16.h>
#include <stdint.h>

#define OUTN   8192
#define INN    8192
#define NGRP   64
#define BATCHN 64
#define BN     64
#define BK     64
#define KSPLIT 8
#define KCHUNK (INN / KSPLIT)      /* 1024 k per ksplit chunk */
#define NITER  (KCHUNK / BK)       /* 16 iters of 64 k */
#define NGRPC  (KCHUNK / 128)      /* 8 quant-groups per chunk */
#define OSZ    (BATCHN * OUTN)     /* 524288 floats = 2 MB */

typedef __attribute__((ext_vector_type(8))) short bf16x8;
typedef __attribute__((ext_vector_type(8))) unsigned short u16x8;
typedef __attribute__((ext_vector_type(4))) float f32x4;
typedef __attribute__((ext_vector_type(4))) unsigned int u32x4;

__device__ __forceinline__ unsigned short f2bf(float f) {
  __hip_bfloat16 h = __float2bfloat16(f);
  return __builtin_bit_cast(unsigned short, h);
}
__device__ __forceinline__ float bf2f(unsigned short h) {
  unsigned int u = ((unsigned int)h) << 16;
  return __builtin_bit_cast(float, u);
}

// async global->LDS, 16B per lane; LDS dest = wave-uniform base + lane*16
__device__ __forceinline__ void gll16(const void* g, void* l) {
  __builtin_amdgcn_global_load_lds(
      (const __attribute__((address_space(1))) unsigned int*)g,
      (__attribute__((address_space(3))) unsigned int*)l, 16, 0, 0);
}

// Per batch row b: (1) x_bf16[b][k] = bf16(x[b][k]) written once (linear layout),
// (2) xsum[g][b] = sum over group g of bf16-rounded x
__global__ void qlin_prep(const float* __restrict__ x, float* __restrict__ xsum,
                          unsigned short* __restrict__ xbf) {
  const int b = blockIdx.x;
  const int t = threadIdx.x;
  const float* xrow = x + (size_t)b * INN + t * 32;
  unsigned short* orow = xbf + (size_t)b * INN + t * 32;
  float s = 0.0f;
#pragma unroll
  for (int c = 0; c < 4; ++c) {
    float4 v0 = *(const float4*)(xrow + c * 8);
    float4 v1 = *(const float4*)(xrow + c * 8 + 4);
    u16x8 h;
    h[0] = f2bf(v0.x); h[1] = f2bf(v0.y); h[2] = f2bf(v0.z); h[3] = f2bf(v0.w);
    h[4] = f2bf(v1.x); h[5] = f2bf(v1.y); h[6] = f2bf(v1.z); h[7] = f2bf(v1.w);
#pragma unroll
    for (int j = 0; j < 8; ++j) s += bf2f(h[j]);
    *(u16x8*)(orow + c * 8) = h;
  }
  __shared__ float parts[256];
  parts[t] = s;
  __syncthreads();
  if (t < NGRP) {
    float g = parts[4 * t] + parts[4 * t + 1] + parts[4 * t + 2] + parts[4 * t + 3];
    xsum[t * BATCHN + b] = g;
  }
}

// Tile per iter: 64 rows x 128 B for both packed (32 int32 = 64 k) and x_bf16
// (64 bf16). Row = 8 chunks of 16 B, XOR-swizzled on the gll SOURCE address
// (m173 pattern), LDS dest linear. Consumer reads chunk c of row r at slot
// r*8 + (c ^ (r&7)) -> conflict-free b128 reads.
//
// Pipeline (T3+T4): 3 LDS buffers, 2 tiles in flight per wave (8 outstanding
// glls), one raw s_barrier per iter preceded by s_waitcnt vmcnt(4) — only the
// oldest tile's 4 loads are drained; the newer 4 ride across the barrier.
//   RAW:  tile i's loads done for every wave before its barrier-pass (each
//         wave waits vmcnt(4) on its own 8 outstanding, FIFO retire).
//   WAR:  issue(i+2) targets buf[(i+2)%3], last read as tile i-1, whose
//         compute finished before THIS iter's barrier in every wave.
__global__ __launch_bounds__(256, 4) void qlin_main(
    const int* __restrict__ packed, const unsigned short* __restrict__ xbf,
    const float* __restrict__ scales, const float* __restrict__ xsum,
    float* __restrict__ out, float* __restrict__ part) {
  const int bx    = blockIdx.x;
  const int ks    = bx & (KSPLIT - 1);
  const int ntile = bx >> 3;
  const int o0    = ntile * BN;
  const int g0    = ks * NGRPC;

  const int t    = threadIdx.x;
  const int lane = t & 63;
  const int w    = t >> 6;        // wave 0..3 owns out cols [w*16, w*16+16)
  const int l15  = lane & 15;
  const int quad = lane >> 4;

  __shared__ __align__(16) int4  pkb[3][512];   // 3 x 8 KB raw packed ints
  __shared__ __align__(16) int4  xb[3][512];    // 3 x 8 KB x bf16
  __shared__ __align__(16) float st[BN][9];     // scales (pad -> conflict-free)
  __shared__ __align__(16) float xs[NGRPC][BATCHN];

  // stage scales (64x8) and group x-sums (8x64) once; visible after iter-0
  // barrier (lgkmcnt(0) folded into the first waitcnt below)
#pragma unroll
  for (int i = 0; i < 2; ++i) {
    int v = t * 2 + i;
    int ol = v >> 3, gl = v & 7;
    st[ol][gl] = scales[(size_t)(o0 + ol) * NGRP + g0 + gl];
    int gl2 = v >> 6, b2 = v & 63;
    xs[gl2][b2] = xsum[(g0 + gl2) * BATCHN + b2];
  }

  // gll source bases. Thread t covers LDS slots t (row t>>3) and 256+t (row +32).
  const int row0 = t >> 3;
  const int p0   = t & 7;
  const int c0   = p0 ^ (row0 & 7);          // swizzled data chunk
  const char* pk0 = (const char*)packed + (size_t)(o0 + row0) * 16384 + ks * 2048 + c0 * 16;
  const char* pk1 = pk0 + (size_t)32 * 16384;
  const char* xg0 = (const char*)xbf + (size_t)row0 * 16384 + ks * 2048 + c0 * 16;
  const char* xg1 = xg0 + (size_t)32 * 16384;

  auto issue = [&](int i, int buf) {
    const size_t off = (size_t)i * 128;
    gll16(pk0 + off, &pkb[buf][t]);
    gll16(pk1 + off, &pkb[buf][256 + t]);
    gll16(xg0 + off, &xb[buf][t]);
    gll16(xg1 + off, &xb[buf][256 + t]);
  };

  f32x4 facc[4], gacc[4];
#pragma unroll
  for (int mt = 0; mt < 4; ++mt) {
    facc[mt] = (f32x4){0.f, 0.f, 0.f, 0.f};
    gacc[mt] = (f32x4){0.f, 0.f, 0.f, 0.f};
  }

  issue(0, 0);
  issue(1, 1);   // 8 vmem ops outstanding entering the loop

  const int browB = w * 16 + l15;   // weight row = output column
  const int sw    = l15 & 7;        // consumer-side XOR

#pragma unroll
  for (int i = 0; i < NITER; ++i) {
    // counted drain: oldest tile only (T4); full drain only on last iter
    if (i == 0)
      asm volatile("s_waitcnt vmcnt(4) lgkmcnt(0)" ::: "memory");
    else if (i == NITER - 1)
      asm volatile("s_waitcnt vmcnt(0)" ::: "memory");
    else
      asm volatile("s_waitcnt vmcnt(4)" ::: "memory");
    __builtin_amdgcn_sched_barrier(0);
    __builtin_amdgcn_s_barrier();
    __builtin_amdgcn_sched_barrier(0);

    if (i + 2 < NITER) issue(i + 2, (i + 2) % 3);   // refill pipeline depth 2

    const int cur = i % 3;
#pragma unroll
    for (int kq = 0; kq < 2; ++kq) {
      const int ch = kq * 4 + quad;             // data chunk: k = ch*8..ch*8+7
      int4 v = pkb[cur][browB * 8 + (ch ^ sw)];
      // byte n -> bf16x2 (128+lo_nibble, 128+hi_nibble); 0x4300 = 128.0bf
      u32x4 bw;
      bw.x = 0x43004300u | ((unsigned)v.x & 0xFu) | (((unsigned)v.x & 0xF0u) << 12);
      bw.y = 0x43004300u | ((unsigned)v.y & 0xFu) | (((unsigned)v.y & 0xF0u) << 12);
      bw.z = 0x43004300u | ((unsigned)v.z & 0xFu) | (((unsigned)v.z & 0xF0u) << 12);
      bw.w = 0x43004300u | ((unsigned)v.w & 0xFu) | (((unsigned)v.w & 0xF0u) << 12);
      bf16x8 bfv = __builtin_bit_cast(bf16x8, bw);
#pragma unroll
      for (int mt = 0; mt < 4; ++mt) {
        bf16x8 af = *(const bf16x8*)&xb[cur][(mt * 16 + l15) * 8 + (ch ^ sw)];
        gacc[mt] = __builtin_amdgcn_mfma_f32_16x16x32_bf16(af, bfv, gacc[mt], 0, 0, 0);
      }
    }

    if (i & 1) {
      // fold group g: y += s[o,g] * (S_g - 136 * xsum_g[b])   (136 = 128 + 8)
      const int g = i >> 1;
      float s0 = st[browB][g];
#pragma unroll
      for (int mt = 0; mt < 4; ++mt) {
        f32x4 xv = *(const f32x4*)&xs[g][mt * 16 + quad * 4];
#pragma unroll
        for (int r = 0; r < 4; ++r) {
          facc[mt][r] += s0 * (gacc[mt][r] - 136.0f * xv[r]);
          gacc[mt][r] = 0.f;
        }
      }
    }
  }

  const int obase = o0 + browB;
  if (part) {
    float* pb = part + (size_t)ks * OSZ;
#pragma unroll
    for (int mt = 0; mt < 4; ++mt)
#pragma unroll
      for (int r = 0; r < 4; ++r) {
        int m = mt * 16 + quad * 4 + r;
        pb[(size_t)m * OUTN + obase] = facc[mt][r];
      }
  } else {
#pragma unroll
    for (int mt = 0; mt < 4; ++mt)
#pragma unroll
      for (int r = 0; r < 4; ++r) {
        int m = mt * 16 + quad * 4 + r;
        atomicAdd(&out[(size_t)m * OUTN + obase], facc[mt][r]);
      }
  }
}

__global__ void qlin_reduce(const float* __restrict__ part, float* __restrict__ out) {
  const size_t i = ((size_t)blockIdx.x * 256 + threadIdx.x) * 4;
  float4 s = *(const float4*)(part + i);
#pragma unroll
  for (int ks = 1; ks < KSPLIT; ++ks) {
    float4 v = *(const float4*)(part + (size_t)ks * OSZ + i);
    s.x += v.x; s.y += v.y; s.z += v.z; s.w += v.w;
  }
  *(float4*)(out + i) = s;
}

extern "C" void kernel_launch(void* const* d_in, const int* in_sizes, int n_in,
                              void* d_out, int out_size, void* d_ws, size_t ws_size,
                              hipStream_t stream) {
  const float* x      = (const float*)d_in[0];
  const int*   packed = (const int*)d_in[1];
  const float* scales = (const float*)d_in[2];
  float* out  = (float*)d_out;

  // ws layout: [0,16K) xsum | [16K, 16K+1M) x_bf16 | [.., +16M) partials
  float*          xsum = (float*)d_ws;
  unsigned short* xbf  = (unsigned short*)((char*)d_ws + 16384);
  const size_t part_off = 16384 + (size_t)BATCHN * INN * 2;
  const size_t need = part_off + (size_t)KSPLIT * OSZ * sizeof(float);
  float* part = (ws_size >= need) ? (float*)((char*)d_ws + part_off) : nullptr;

  qlin_prep<<<BATCHN, 256, 0, stream>>>(x, xsum, xbf);
  if (!part)
    hipMemsetAsync(d_out, 0, (size_t)out_size * sizeof(float), stream);
  qlin_main<<<(OUTN / BN) * KSPLIT, 256, 0, stream>>>(packed, xbf, scales, xsum, out, part);
  if (part)
    qlin_reduce<<<OSZ / 4 / 256, 256, 0, stream>>>(part, out);
}

// Round 4
// 209.296 us; speedup vs baseline: 1.3438x; 1.0145x over previous
//
#include <hip/hip_runtime.h>
#include <hip/hip_bf16.h>
#include <stdint.h>

#define OUTN   8192
#define INN    8192
#define NGRP   64
#define BATCHN 64
#define BN     64
#define BK     64
#define KSPLIT 8
#define KCHUNK (INN / KSPLIT)      /* 1024 k per ksplit chunk */
#define NITER  (KCHUNK / BK)       /* 16 iters of 64 k */
#define NGRPC  (KCHUNK / 128)      /* 8 quant-groups per chunk */
#define OSZ    (BATCHN * OUTN)     /* 524288 floats = 2 MB */

typedef __attribute__((ext_vector_type(8))) short bf16x8;
typedef __attribute__((ext_vector_type(8))) unsigned short u16x8;
typedef __attribute__((ext_vector_type(4))) float f32x4;
typedef __attribute__((ext_vector_type(4))) unsigned int u32x4;

__device__ __forceinline__ unsigned short f2bf(float f) {
  __hip_bfloat16 h = __float2bfloat16(f);
  return __builtin_bit_cast(unsigned short, h);
}
__device__ __forceinline__ float bf2f(unsigned short h) {
  unsigned int u = ((unsigned int)h) << 16;
  return __builtin_bit_cast(float, u);
}

// async global->LDS, 16B per lane; LDS dest = wave-uniform base + lane*16
__device__ __forceinline__ void gll16(const void* g, void* l) {
  __builtin_amdgcn_global_load_lds(
      (const __attribute__((address_space(1))) unsigned int*)g,
      (__attribute__((address_space(3))) unsigned int*)l, 16, 0, 0);
}

// Per batch row b: (1) x_bf16[b][k] = bf16(x[b][k]) written once,
// (2) xsum[g][b] = sum over group g of bf16-rounded x
__global__ void qlin_prep(const float* __restrict__ x, float* __restrict__ xsum,
                          unsigned short* __restrict__ xbf) {
  const int b = blockIdx.x;
  const int t = threadIdx.x;
  const float* xrow = x + (size_t)b * INN + t * 32;
  unsigned short* orow = xbf + (size_t)b * INN + t * 32;
  float s = 0.0f;
#pragma unroll
  for (int c = 0; c < 4; ++c) {
    float4 v0 = *(const float4*)(xrow + c * 8);
    float4 v1 = *(const float4*)(xrow + c * 8 + 4);
    u16x8 h;
    h[0] = f2bf(v0.x); h[1] = f2bf(v0.y); h[2] = f2bf(v0.z); h[3] = f2bf(v0.w);
    h[4] = f2bf(v1.x); h[5] = f2bf(v1.y); h[6] = f2bf(v1.z); h[7] = f2bf(v1.w);
#pragma unroll
    for (int j = 0; j < 8; ++j) s += bf2f(h[j]);
    *(u16x8*)(orow + c * 8) = h;
  }
  __shared__ float parts[256];
  parts[t] = s;
  __syncthreads();
  if (t < NGRP) {
    float g = parts[4 * t] + parts[4 * t + 1] + parts[4 * t + 2] + parts[4 * t + 3];
    xsum[t * BATCHN + b] = g;
  }
}

// packed: ZERO cross-wave reuse -> direct global->register, pipelined 1 tile
// ahead in 2 static register sets (no LDS round-trip, no barrier dependency).
// xbf: reused by all 4 waves -> gll16 into 3 LDS buffers, 2 tiles in flight.
// Per-iter issue order P(next tile, 2 loads) then G(tile+2, 2 glls) makes the
// FIFO retire exactly {P_i, G_i} at a counted s_waitcnt vmcnt(2):
//   prologue Q=[P0,P0,G0,G0,G1,G1]; iter i: vmcnt(2) retires P_i,G_i;
//   issue P_{i+1},G_{i+2} -> Q=[G_{i+1}x2,P_{i+1}x2,G_{i+2}x2]. Tail peels to
//   vmcnt(0). WAR: G_{i+2} targets xb[(i+2)%3], last read at tile i-1, done in
//   all waves before this iter's barrier; P regs are per-wave (program order).
__global__ __launch_bounds__(256, 4) void qlin_main(
    const int* __restrict__ packed, const unsigned short* __restrict__ xbf,
    const float* __restrict__ scales, const float* __restrict__ xsum,
    float* __restrict__ out, float* __restrict__ part) {
  const int bx    = blockIdx.x;
  const int ks    = bx & (KSPLIT - 1);
  const int ntile = bx >> 3;
  const int o0    = ntile * BN;
  const int g0    = ks * NGRPC;

  const int t    = threadIdx.x;
  const int lane = t & 63;
  const int w    = t >> 6;        // wave 0..3 owns out cols [w*16, w*16+16)
  const int l15  = lane & 15;
  const int quad = lane >> 4;

  __shared__ __align__(16) int4  xb[3][512];    // 3 x 8 KB x bf16
  __shared__ __align__(16) float st[BN][9];     // scales (pad -> conflict-free)
  __shared__ __align__(16) float xs[NGRPC][BATCHN];

  // stage scales (64x8) and group x-sums (8x64); visible after iter-0 barrier
#pragma unroll
  for (int i = 0; i < 2; ++i) {
    int v = t * 2 + i;
    int ol = v >> 3, gl = v & 7;
    st[ol][gl] = scales[(size_t)(o0 + ol) * NGRP + g0 + gl];
    int gl2 = v >> 6, b2 = v & 63;
    xs[gl2][b2] = xsum[(g0 + gl2) * BATCHN + b2];
  }

  const int browB = w * 16 + l15;   // weight row = output column
  const int sw    = l15 & 7;        // consumer-side LDS XOR

  // xbf gll sources: thread t covers LDS slots t (row t>>3) and 256+t (row+32);
  // chunk XOR-swizzled on the SOURCE (m173), LDS linear; read back with ch^sw.
  const int row0 = t >> 3;
  const int c0   = (t & 7) ^ (row0 & 7);
  const char* xg0 = (const char*)xbf + (size_t)row0 * 16384 + ks * 2048 + c0 * 16;
  const char* xg1 = xg0 + (size_t)32 * 16384;

  auto issueG = [&](int i, int buf) {
    const size_t off = (size_t)i * 128;
    gll16(xg0 + off, &xb[buf][t]);
    gll16(xg1 + off, &xb[buf][256 + t]);
  };

  // packed per-lane base: row browB, 16B chunk quad (kq stride 64B, iter 128B)
  const char* pkL = (const char*)packed + (size_t)(o0 + browB) * 16384 +
                    ks * 2048 + quad * 16;

  int4 pkE[2], pkO[2];   // even-/odd-tile packed registers (static indexing)

  f32x4 facc[4], gacc[4];
#pragma unroll
  for (int mt = 0; mt < 4; ++mt) {
    facc[mt] = (f32x4){0.f, 0.f, 0.f, 0.f};
    gacc[mt] = (f32x4){0.f, 0.f, 0.f, 0.f};
  }

  // prologue: P0 then G0, G1  ->  Q=[P0,P0,G0,G0,G1,G1]
  pkE[0] = *(const int4*)(pkL);
  pkE[1] = *(const int4*)(pkL + 64);
  __builtin_amdgcn_sched_barrier(0);
  issueG(0, 0);
  issueG(1, 1);
  __builtin_amdgcn_sched_barrier(0);

#pragma unroll
  for (int i = 0; i < NITER; ++i) {
    if (i == 0)
      asm volatile("s_waitcnt vmcnt(2) lgkmcnt(0)" ::: "memory");
    else if (i == NITER - 1)
      asm volatile("s_waitcnt vmcnt(0)" ::: "memory");
    else
      asm volatile("s_waitcnt vmcnt(2)" ::: "memory");
    __builtin_amdgcn_sched_barrier(0);
    __builtin_amdgcn_s_barrier();
    __builtin_amdgcn_sched_barrier(0);

    // refill: P_{i+1} first, then G_{i+2} (order matters for the FIFO count)
    if (i + 1 < NITER) {
      const char* p = pkL + (size_t)(i + 1) * 128;
      if ((i + 1) & 1) { pkO[0] = *(const int4*)p; pkO[1] = *(const int4*)(p + 64); }
      else             { pkE[0] = *(const int4*)p; pkE[1] = *(const int4*)(p + 64); }
    }
    if (i + 2 < NITER) issueG(i + 2, (i + 2) % 3);
    __builtin_amdgcn_sched_barrier(0);

    const int cur = i % 3;
#pragma unroll
    for (int kq = 0; kq < 2; ++kq) {
      const int ch = kq * 4 + quad;             // data chunk: k = ch*8..ch*8+7
      int4 v = (i & 1) ? pkO[kq] : pkE[kq];
      // byte n -> bf16x2 (128+lo_nibble, 128+hi_nibble); 0x4300 = 128.0bf
      u32x4 bw;
      bw.x = 0x43004300u | ((unsigned)v.x & 0xFu) | (((unsigned)v.x & 0xF0u) << 12);
      bw.y = 0x43004300u | ((unsigned)v.y & 0xFu) | (((unsigned)v.y & 0xF0u) << 12);
      bw.z = 0x43004300u | ((unsigned)v.z & 0xFu) | (((unsigned)v.z & 0xF0u) << 12);
      bw.w = 0x43004300u | ((unsigned)v.w & 0xFu) | (((unsigned)v.w & 0xF0u) << 12);
      bf16x8 bfv = __builtin_bit_cast(bf16x8, bw);
#pragma unroll
      for (int mt = 0; mt < 4; ++mt) {
        bf16x8 af = *(const bf16x8*)&xb[cur][(mt * 16 + l15) * 8 + (ch ^ sw)];
        gacc[mt] = __builtin_amdgcn_mfma_f32_16x16x32_bf16(af, bfv, gacc[mt], 0, 0, 0);
      }
    }

    if (i & 1) {
      // fold group g: y += s[o,g] * (S_g - 136 * xsum_g[b])   (136 = 128 + 8)
      const int g = i >> 1;
      float s0 = st[browB][g];
#pragma unroll
      for (int mt = 0; mt < 4; ++mt) {
        f32x4 xv = *(const f32x4*)&xs[g][mt * 16 + quad * 4];
#pragma unroll
        for (int r = 0; r < 4; ++r) {
          facc[mt][r] += s0 * (gacc[mt][r] - 136.0f * xv[r]);
          gacc[mt][r] = 0.f;
        }
      }
    }
  }

  const int obase = o0 + browB;
  if (part) {
    float* pb = part + (size_t)ks * OSZ;
#pragma unroll
    for (int mt = 0; mt < 4; ++mt)
#pragma unroll
      for (int r = 0; r < 4; ++r) {
        int m = mt * 16 + quad * 4 + r;
        pb[(size_t)m * OUTN + obase] = facc[mt][r];
      }
  } else {
#pragma unroll
    for (int mt = 0; mt < 4; ++mt)
#pragma unroll
      for (int r = 0; r < 4; ++r) {
        int m = mt * 16 + quad * 4 + r;
        atomicAdd(&out[(size_t)m * OUTN + obase], facc[mt][r]);
      }
  }
}

__global__ void qlin_reduce(const float* __restrict__ part, float* __restrict__ out) {
  const size_t i = ((size_t)blockIdx.x * 256 + threadIdx.x) * 4;
  float4 s = *(const float4*)(part + i);
#pragma unroll
  for (int ks = 1; ks < KSPLIT; ++ks) {
    float4 v = *(const float4*)(part + (size_t)ks * OSZ + i);
    s.x += v.x; s.y += v.y; s.z += v.z; s.w += v.w;
  }
  *(float4*)(out + i) = s;
}

extern "C" void kernel_launch(void* const* d_in, const int* in_sizes, int n_in,
                              void* d_out, int out_size, void* d_ws, size_t ws_size,
                              hipStream_t stream) {
  const float* x      = (const float*)d_in[0];
  const int*   packed = (const int*)d_in[1];
  const float* scales = (const float*)d_in[2];
  float* out  = (float*)d_out;

  // ws layout: [0,16K) xsum | [16K, 16K+1M) x_bf16 | [.., +16M) partials
  float*          xsum = (float*)d_ws;
  unsigned short* xbf  = (unsigned short*)((char*)d_ws + 16384);
  const size_t part_off = 16384 + (size_t)BATCHN * INN * 2;
  const size_t need = part_off + (size_t)KSPLIT * OSZ * sizeof(float);
  float* part = (ws_size >= need) ? (float*)((char*)d_ws + part_off) : nullptr;

  qlin_prep<<<BATCHN, 256, 0, stream>>>(x, xsum, xbf);
  if (!part)
    hipMemsetAsync(d_out, 0, (size_t)out_size * sizeof(float), stream);
  qlin_main<<<(OUTN / BN) * KSPLIT, 256, 0, stream>>>(packed, xbf, scales, xsum, out, part);
  if (part)
    qlin_reduce<<<OSZ / 4 / 256, 256, 0, stream>>>(part, out);
}